// Round 16
// baseline (4867.199 us; speedup 1.0000x reference)
//
#include <hip/hip_runtime.h>
#include <math.h>

#define TT 2048
#define BB 64
#define II 64
#define HH 512
#define OO 32
#define OCC 8
#define QS 128   // k/h slice per WG (4-way split)
#define WT_LD 48 // padded leading dim of packed readout weights

// d_out layout: output [T,B,32] | output_ctx [T,B,8] | rate_all [T,B,512]
#define OUT1_OFF ((size_t)TT * BB * OO)
#define RATE_OFF (OUT1_OFF + (size_t)TT * BB * OCC)

// d_ws layout: P[B][4][2][HH] floats (1 MB) | flags @1MB (16KB) | Wt @2MB (96KB)
#define FLAG_BYTE_OFF ((size_t)1 << 20)
#define FLAG_BYTES (BB * 4 * 16 * sizeof(int))
#define WT_BYTE_OFF ((size_t)2 << 20)

// ---------------------------------------------------------------------------
// Pack Wt[h][o] = Wo[o][h] / Woc[o-32][h] / pad  (coalesced readout weights)
// ---------------------------------------------------------------------------
__global__ __launch_bounds__(256) void pack_wt(
    const float* __restrict__ Wo, const float* __restrict__ Woc,
    float* __restrict__ Wt)
{
    int idx = blockIdx.x * 256 + threadIdx.x;
    if (idx >= HH * WT_LD) return;
    int h = idx / WT_LD, o = idx % WT_LD;
    float v = 0.f;
    if (o < OO)            v = Wo[(size_t)o * HH + h];
    else if (o < OO + OCC) v = Woc[(size_t)(o - OO) * HH + h];
    Wt[idx] = v;
}

// ---------------------------------------------------------------------------
// Recurrent scan, r12 protocol with 512-THREAD WGs (8 waves, 2/SIMD):
// every barrier syncs 8 waves instead of 16 -> the skew term r13-r15 could
// not remove in software shrinks by construction; dot cycles unchanged
// (same per-SIMD FMA count); VGPR cap at 2 waves/SIMD is 256 (not r5's 128).
// Thread (g = tid>>6, ht = tid&63): 16 k-rows [kq,kq+16), 8 h-cols [8ht,8ht+8).
// Weights register-resident: 32 float4 = 128 floats/thread.
// SYNC RULES (hard-won): r8: flag store (tid 0) and pollers (tids 64/128/192,
// waves 1-3) in disjoint waves; no store gated behind a poll. r10: poll
// traffic O(3)/WG. r4: relaxed agent atomics only. r13/r14/r15: plain
// __syncthreads everywhere; no wave-specialized publishers; no asm barriers.
// FP order bit-identical to r12 (k ascending per h; reduce p=0..7; j=1..3).
// ---------------------------------------------------------------------------
__global__ __launch_bounds__(512) void rnn_scan16(
    const float* __restrict__ x,       // [T,B,I]
    const float* __restrict__ rate0,   // [B,H]
    const float* __restrict__ noise,   // [T,B,H]
    const float* __restrict__ Wh,      // [H,H] row-major
    const float* __restrict__ Wi,      // [H,I]
    const float* __restrict__ bi,
    const float* __restrict__ bh,
    float* __restrict__ rate_out,      // [T,B,H]
    float* P,                          // [B][4][2][HH]
    int* flags)                        // [B*4*16]
{
    __shared__ float  st[QS];          // own state slice
    __shared__ float  parts[8 * HH];   // per-g partials (16 KB)
    __shared__ float4 wi4[II / 4][QS]; // Wi slice, [c4][l]
    __shared__ float4 xbuf4[II / 4];   // x_t

    const int bid = blockIdx.x;
    const int q   = bid >> 6;          // quarter 0..3
    const int b   = bid & 63;          // batch
    const int tid = threadIdx.x;
    const int g   = tid >> 6;          // 0..7 -> 16 k-rows each
    const int ht  = tid & 63;
    const int h8  = 8 * ht;            // 8 consecutive h-cols per thread
    const int kq  = q * QS + g * 16;

    const double SIG = 1.5 / sqrt(512.0);
    const float  NS  = (float)sqrt(2.0 * SIG * SIG / 0.1);

    // Weights register-resident: wregA[m]=W^T[kq+m][h8..h8+4), wregB: +4..8
    float4 wregA[16], wregB[16];
    #pragma unroll
    for (int m = 0; m < 16; ++m) {
        wregA[m].x = Wh[(size_t)(h8 + 0) * HH + kq + m];
        wregA[m].y = Wh[(size_t)(h8 + 1) * HH + kq + m];
        wregA[m].z = Wh[(size_t)(h8 + 2) * HH + kq + m];
        wregA[m].w = Wh[(size_t)(h8 + 3) * HH + kq + m];
        wregB[m].x = Wh[(size_t)(h8 + 4) * HH + kq + m];
        wregB[m].y = Wh[(size_t)(h8 + 5) * HH + kq + m];
        wregB[m].z = Wh[(size_t)(h8 + 6) * HH + kq + m];
        wregB[m].w = Wh[(size_t)(h8 + 7) * HH + kq + m];
    }

    // Wi rows of own h-slice -> LDS (one-time)
    for (int i = tid; i < QS * (II / 4); i += 512) {
        int l2 = i >> 4, c4 = i & 15;
        wi4[c4][l2] = *(const float4*)&Wi[(size_t)(q * QS + l2) * II + 4 * c4];
    }

    const bool inband = (tid >= q * QS) && (tid < q * QS + QS);
    const int  l      = tid - q * QS;  // local h index when inband
    float rf = 0.f, bsum = 0.f;
    if (inband) {
        rf   = rate0[b * HH + tid];
        bsum = bi[tid] + bh[tid];
    }
    if (tid < QS) st[tid] = rate0[b * HH + q * QS + tid];
    int* myflag = &flags[(b * 4 + q) * 16];
    __syncthreads();

    for (int t = 0; t < TT; ++t) {
        const int par = t & 1;
        const size_t row = ((size_t)t * BB + b) * HH;

        // stage x_t (read after B1 in prefold; next overwrite after B4)
        if (tid < II / 4)
            xbuf4[tid] = *(const float4*)&x[((size_t)t * BB + b) * II + 4 * tid];
        float nz = 0.f;
        if (inband) nz = noise[row + tid];    // early; consumed post-flag

        // ---- dot: 8 h-cols over 16 k-rows (st wave-broadcast); k ascending
        float a0 = 0.f, a1 = 0.f, a2 = 0.f, a3 = 0.f;
        float b0 = 0.f, b1 = 0.f, b2 = 0.f, b3 = 0.f;
        #pragma unroll
        for (int mm = 0; mm < 4; ++mm) {
            float4 s4 = *(const float4*)&st[g * 16 + 4 * mm];
            a0 += wregA[4*mm].x*s4.x + wregA[4*mm+1].x*s4.y + wregA[4*mm+2].x*s4.z + wregA[4*mm+3].x*s4.w;
            a1 += wregA[4*mm].y*s4.x + wregA[4*mm+1].y*s4.y + wregA[4*mm+2].y*s4.z + wregA[4*mm+3].y*s4.w;
            a2 += wregA[4*mm].z*s4.x + wregA[4*mm+1].z*s4.y + wregA[4*mm+2].z*s4.z + wregA[4*mm+3].z*s4.w;
            a3 += wregA[4*mm].w*s4.x + wregA[4*mm+1].w*s4.y + wregA[4*mm+2].w*s4.z + wregA[4*mm+3].w*s4.w;
            b0 += wregB[4*mm].x*s4.x + wregB[4*mm+1].x*s4.y + wregB[4*mm+2].x*s4.z + wregB[4*mm+3].x*s4.w;
            b1 += wregB[4*mm].y*s4.x + wregB[4*mm+1].y*s4.y + wregB[4*mm+2].y*s4.z + wregB[4*mm+3].y*s4.w;
            b2 += wregB[4*mm].z*s4.x + wregB[4*mm+1].z*s4.y + wregB[4*mm+2].z*s4.z + wregB[4*mm+3].z*s4.w;
            b3 += wregB[4*mm].w*s4.x + wregB[4*mm+1].w*s4.y + wregB[4*mm+2].w*s4.z + wregB[4*mm+3].w*s4.w;
        }
        *(float4*)&parts[g * HH + h8]     = make_float4(a0, a1, a2, a3);
        *(float4*)&parts[g * HH + h8 + 4] = make_float4(b0, b1, b2, b3);
        __syncthreads();                      // B1: parts + xbuf ready

        // ---- reduce over g (all 512 threads own h = tid); publish peers
        float s = 0.f;
        #pragma unroll
        for (int p = 0; p < 8; ++p) s += parts[p * HH + tid];
        if (!inband)
            __hip_atomic_store(&P[(((size_t)b * 4 + q) * 2 + par) * HH + tid], s,
                               __ATOMIC_RELAXED, __HIP_MEMORY_SCOPE_AGENT);
        __syncthreads();                      // B2: full drain -> P at IF

        // ---- flag publish (wave 0, immediately after B2)
        if (tid == 0)
            __hip_atomic_store(myflag, t + 1, __ATOMIC_RELAXED,
                               __HIP_MEMORY_SCOPE_AGENT);

        // ---- fused prefold: hides under the poll window
        float pre = 0.f;
        if (inband) {
            pre = bsum + NS * nz;
            #pragma unroll
            for (int c4 = 0; c4 < II / 4; ++c4) {
                float4 wv4 = wi4[c4][l];
                float4 xv  = xbuf4[c4];
                pre += wv4.x * xv.x + wv4.y * xv.y + wv4.z * xv.z + wv4.w * xv.w;
            }
        }

        // ---- peer polls (waves 1..3; store above precedes polls -- r8 rule)
        if (tid == 64 || tid == 128 || tid == 192) {
            int* f = &flags[(b * 4 + ((q + (tid >> 6)) & 3)) * 16];
            while (__hip_atomic_load(f, __ATOMIC_RELAXED,
                                     __HIP_MEMORY_SCOPE_AGENT) < t + 1) {}
        }
        __syncthreads();                      // B3: peers' P published

        // ---- consume: own-slice update (consumer reuses its own s)
        if (inband) {
            float tot = pre + s;
            #pragma unroll
            for (int j = 1; j < 4; ++j) {
                const int pj = (q + j) & 3;
                tot += __hip_atomic_load(
                    &P[(((size_t)b * 4 + pj) * 2 + par) * HH + tid],
                    __ATOMIC_RELAXED, __HIP_MEMORY_SCOPE_AGENT);
            }
            rf = 0.9f * rf + 0.1f * tanhf(tot);
            rate_out[row + tid] = rf;
            st[l] = rf;
        }
        __syncthreads();                      // B4: st ready for next dot
    }
}

// ---------------------------------------------------------------------------
// Readout: 32 rows staged; each weight load amortized over 2 rows (r15, ~160us)
// ---------------------------------------------------------------------------
__global__ __launch_bounds__(512) void readout3(
    const float* __restrict__ rate_all,
    const float* __restrict__ Wt,   // [512][48] packed [Wo | Woc | pad]
    const float* __restrict__ bo, const float* __restrict__ boc,
    float* __restrict__ out, float* __restrict__ outc)
{
    __shared__ float rbuf[32][HH];  // 64 KB
    const int tid  = threadIdx.x;
    const size_t row0 = (size_t)blockIdx.x * 32;

    for (int i = tid; i < 32 * (HH / 4); i += 512) {
        int r = i >> 7, c = (i & 127) * 4;
        *(float4*)&rbuf[r][c] = *(const float4*)&rate_all[(row0 + r) * HH + c];
    }
    __syncthreads();

    {
        const int r = tid >> 5, o = tid & 31;
        const float* wt = Wt + o;
        float acc0 = 0.f, acc1 = 0.f;
        #pragma unroll 8
        for (int h = 0; h < HH; ++h) {
            float w = wt[(size_t)h * WT_LD];
            acc0 += rbuf[r][h] * w;
            acc1 += rbuf[r + 16][h] * w;
        }
        out[(row0 + r) * OO + o]      = acc0 + bo[o];
        out[(row0 + r + 16) * OO + o] = acc1 + bo[o];
    }
    if (tid < 128) {
        const int r = tid >> 3, c = tid & 7;
        const float* wt = Wt + OO + c;
        float acc0 = 0.f, acc1 = 0.f;
        #pragma unroll 8
        for (int h = 0; h < HH; ++h) {
            float w = wt[(size_t)h * WT_LD];
            acc0 += rbuf[r][h] * w;
            acc1 += rbuf[r + 16][h] * w;
        }
        outc[(row0 + r) * OCC + c]      = acc0 + boc[c];
        outc[(row0 + r + 16) * OCC + c] = acc1 + boc[c];
    }
}

// ---------------------------------------------------------------------------
extern "C" void kernel_launch(void* const* d_in, const int* in_sizes, int n_in,
                              void* d_out, int out_size, void* d_ws, size_t ws_size,
                              hipStream_t stream)
{
    const float* x     = (const float*)d_in[0];
    const float* rate0 = (const float*)d_in[1];
    const float* noise = (const float*)d_in[2];
    const float* Wi    = (const float*)d_in[3];
    const float* bi    = (const float*)d_in[4];
    const float* Wh    = (const float*)d_in[5];
    const float* bh    = (const float*)d_in[6];
    const float* Wo    = (const float*)d_in[7];
    const float* bo    = (const float*)d_in[8];
    const float* Woc   = (const float*)d_in[9];
    const float* boc   = (const float*)d_in[10];

    float* out   = (float*)d_out;
    float* rateb = out + RATE_OFF;
    float* P     = (float*)d_ws;
    int*   flags = (int*)((char*)d_ws + FLAG_BYTE_OFF);
    float* Wt    = (float*)((char*)d_ws + WT_BYTE_OFF);

    hipMemsetAsync(flags, 0, FLAG_BYTES, stream);   // ws is not re-poisoned
    pack_wt<<<(HH * WT_LD + 255) / 256, 256, 0, stream>>>(Wo, Woc, Wt);
    rnn_scan16<<<4 * BB, 512, 0, stream>>>(x, rate0, noise, Wh, Wi, bi, bh,
                                           rateb, P, flags);
    readout3<<<TT * BB / 32, 512, 0, stream>>>(rateb, Wt, bo, boc,
                                               out, out + OUT1_OFF);
}

// Round 17
// 4761.013 us; speedup vs baseline: 1.0223x; 1.0223x over previous
//
#include <hip/hip_runtime.h>
#include <math.h>

#define TT 2048
#define BB 64
#define II 64
#define HH 512
#define OO 32
#define OCC 8
#define QS 128   // k/h slice per WG (4-way split)
#define WT_LD 48 // padded leading dim of packed readout weights

// d_out layout: output [T,B,32] | output_ctx [T,B,8] | rate_all [T,B,512]
#define OUT1_OFF ((size_t)TT * BB * OO)
#define RATE_OFF (OUT1_OFF + (size_t)TT * BB * OCC)

// d_ws layout: P[B][4][2][HH] floats (1 MB) | flags @1MB (16KB) | Wt @2MB (96KB)
#define FLAG_BYTE_OFF ((size_t)1 << 20)
#define FLAG_BYTES (BB * 4 * 16 * sizeof(int))
#define WT_BYTE_OFF ((size_t)2 << 20)

// ---------------------------------------------------------------------------
// Pack Wt[h][o] = Wo[o][h] / Woc[o-32][h] / pad  (coalesced readout weights)
// ---------------------------------------------------------------------------
__global__ __launch_bounds__(256) void pack_wt(
    const float* __restrict__ Wo, const float* __restrict__ Woc,
    float* __restrict__ Wt)
{
    int idx = blockIdx.x * 256 + threadIdx.x;
    if (idx >= HH * WT_LD) return;
    int h = idx / WT_LD, o = idx % WT_LD;
    float v = 0.f;
    if (o < OO)            v = Wo[(size_t)o * HH + h];
    else if (o < OO + OCC) v = Woc[(size_t)(o - OO) * HH + h];
    Wt[idx] = v;
}

// ---------------------------------------------------------------------------
// Recurrent scan = EXACT r12 structure (proven 4.56 ms: 1024 threads, full
// __syncthreads barriers, parallel reduce + single flag) with ONE delta:
// noise/x are register double-buffered one step ahead, with the t+1 loads
// issued between B1's reduce and the P publish -> they drain at B2 together
// with the P-store acks (paid by the protocol anyway) instead of exposing
// ~200-400 cyc of HBM latency at B1 each step (r12's hidden cost).
// SYNC RULES (hard-won): r8: flag store (tid 0) and pollers (tids
// 64/128/192) in disjoint waves; no store gated behind a poll. r10: poll
// traffic O(3)/WG; consumers read remote P exactly once. r4: relaxed
// agent-scope atomics only (IF-direct, no cache maintenance). r13-r16:
// plain __syncthreads everywhere; no wave-specialized publishers; no asm
// barriers; 1024 threads beats 512.
// FP order bit-identical to r12 (k ascending per h; reduce p=0..7; j=1..3).
// ---------------------------------------------------------------------------
__global__ __launch_bounds__(1024) void rnn_scan17(
    const float* __restrict__ x,       // [T,B,I]
    const float* __restrict__ rate0,   // [B,H]
    const float* __restrict__ noise,   // [T,B,H]
    const float* __restrict__ Wh,      // [H,H] row-major
    const float* __restrict__ Wi,      // [H,I]
    const float* __restrict__ bi,
    const float* __restrict__ bh,
    float* __restrict__ rate_out,      // [T,B,H]
    float* P,                          // [B][4][2][HH]
    int* flags)                        // [B*4*16]
{
    __shared__ float  st[QS];          // own state slice
    __shared__ float  parts[8 * HH];   // per-g partials (16 KB)
    __shared__ float4 wi4[II / 4][QS]; // Wi slice, [c4][l]
    __shared__ float4 xbuf4[II / 4];   // x_t

    const int bid = blockIdx.x;
    const int q   = bid >> 6;          // quarter 0..3
    const int b   = bid & 63;          // batch
    const int tid = threadIdx.x;
    const int g   = tid >> 7;          // 0..7 -> 16 k-rows each
    const int ht  = tid & 127;
    const int h4  = 4 * ht;
    const int kq  = q * QS + g * 16;

    const double SIG = 1.5 / sqrt(512.0);
    const float  NS  = (float)sqrt(2.0 * SIG * SIG / 0.1);

    // Wh weights fully register-resident: wreg[m] = W^T[kq+m][h4..h4+3]
    float4 wreg[16];
    #pragma unroll
    for (int m = 0; m < 16; ++m) {
        wreg[m].x = Wh[(size_t)(h4 + 0) * HH + kq + m];
        wreg[m].y = Wh[(size_t)(h4 + 1) * HH + kq + m];
        wreg[m].z = Wh[(size_t)(h4 + 2) * HH + kq + m];
        wreg[m].w = Wh[(size_t)(h4 + 3) * HH + kq + m];
    }

    // Wi rows of own h-slice -> LDS (one-time)
    for (int i = tid; i < QS * (II / 4); i += 1024) {
        int l2 = i >> 4, c4 = i & 15;
        wi4[c4][l2] = *(const float4*)&Wi[(size_t)(q * QS + l2) * II + 4 * c4];
    }

    const bool inband = (tid >= q * QS) && (tid < q * QS + QS);
    const int  l      = tid - q * QS;  // local h index when inband
    float rf = 0.f, bsum = 0.f;
    if (inband) {
        rf   = rate0[b * HH + tid];
        bsum = bi[tid] + bh[tid];
    }
    if (tid < QS) st[tid] = rate0[b * HH + q * QS + tid];
    int* myflag = &flags[(b * 4 + q) * 16];

    // prologue prefetch: noise(0) in reg; x(0) in LDS; x(1) in reg
    float nz_cur = 0.f;
    if (inband) nz_cur = noise[(size_t)b * HH + tid];
    float4 xreg = make_float4(0.f, 0.f, 0.f, 0.f);
    if (tid < II / 4) {
        xbuf4[tid] = *(const float4*)&x[(size_t)b * II + 4 * tid];
        xreg = *(const float4*)&x[((size_t)BB + b) * II + 4 * tid];
    }
    __syncthreads();

    for (int t = 0; t < TT; ++t) {
        const int par = t & 1;
        const size_t row = ((size_t)t * BB + b) * HH;

        // ---- dot: this thread's 4 h-cols over its 16 k-rows (st broadcast)
        float a0 = 0.f, a1 = 0.f, a2 = 0.f, a3 = 0.f;
        #pragma unroll
        for (int mm = 0; mm < 4; ++mm) {
            float4 s4 = *(const float4*)&st[g * 16 + 4 * mm];
            a0 += wreg[4*mm].x*s4.x + wreg[4*mm+1].x*s4.y + wreg[4*mm+2].x*s4.z + wreg[4*mm+3].x*s4.w;
            a1 += wreg[4*mm].y*s4.x + wreg[4*mm+1].y*s4.y + wreg[4*mm+2].y*s4.z + wreg[4*mm+3].y*s4.w;
            a2 += wreg[4*mm].z*s4.x + wreg[4*mm+1].z*s4.y + wreg[4*mm+2].z*s4.z + wreg[4*mm+3].z*s4.w;
            a3 += wreg[4*mm].w*s4.x + wreg[4*mm+1].w*s4.y + wreg[4*mm+2].w*s4.z + wreg[4*mm+3].w*s4.w;
        }
        *(float4*)&parts[g * HH + h4] = make_float4(a0, a1, a2, a3);
        __syncthreads();                      // B1: parts ready (no vmem pending)

        // ---- reduce over g; issue t+1 prefetches; publish peer bands
        float s = 0.f;
        float nz_next = 0.f;
        if (tid < HH) {
            #pragma unroll
            for (int p = 0; p < 8; ++p) s += parts[p * HH + tid];
        }
        // prefetch loads drain at B2 alongside the P-store acks (free)
        if (inband && t + 1 < TT)
            nz_next = noise[row + BB * HH + tid];
        if (tid < II / 4 && t + 2 < TT)
            ;  // xreg refresh issued below after its LDS hand-off point
        if (tid < HH && !inband)
            __hip_atomic_store(&P[(((size_t)b * 4 + q) * 2 + par) * HH + tid], s,
                               __ATOMIC_RELAXED, __HIP_MEMORY_SCOPE_AGENT);
        __syncthreads();                      // B2: full drain -> P at IF

        // ---- flag publish (wave 0, immediately after B2)
        if (tid == 0)
            __hip_atomic_store(myflag, t + 1, __ATOMIC_RELAXED,
                               __HIP_MEMORY_SCOPE_AGENT);

        // ---- fused prefold (uses prefetched nz_cur + xbuf4): poll-shadowed
        float pre = 0.f;
        if (inband) {
            pre = bsum + NS * nz_cur;
            #pragma unroll
            for (int c4 = 0; c4 < II / 4; ++c4) {
                float4 wv4 = wi4[c4][l];
                float4 xv  = xbuf4[c4];
                pre += wv4.x * xv.x + wv4.y * xv.y + wv4.z * xv.z + wv4.w * xv.w;
            }
        }

        // ---- peer polls (waves 1..3; store above precedes polls -- r8 rule)
        if (tid == 64 || tid == 128 || tid == 192) {
            int* f = &flags[(b * 4 + ((q + (tid >> 6)) & 3)) * 16];
            while (__hip_atomic_load(f, __ATOMIC_RELAXED,
                                     __HIP_MEMORY_SCOPE_AGENT) < t + 1) {}
        }
        __syncthreads();                      // B3: peers' P published

        // ---- x hand-off: x(t+1) regs -> LDS; issue x(t+2) load
        if (tid < II / 4) {
            xbuf4[tid] = xreg;                // consumed in t+1's prefold
            if (t + 2 < TT)
                xreg = *(const float4*)&x[((size_t)(t + 2) * BB + b) * II + 4 * tid];
        }

        // ---- consume: own-slice update (consumer reuses its own s)
        if (inband) {
            float tot = pre + s;
            #pragma unroll
            for (int j = 1; j < 4; ++j) {
                const int pj = (q + j) & 3;
                tot += __hip_atomic_load(
                    &P[(((size_t)b * 4 + pj) * 2 + par) * HH + tid],
                    __ATOMIC_RELAXED, __HIP_MEMORY_SCOPE_AGENT);
            }
            rf = 0.9f * rf + 0.1f * tanhf(tot);
            rate_out[row + tid] = rf;
            st[l] = rf;
        }
        nz_cur = nz_next;
        __syncthreads();                      // B4: st + xbuf ready for t+1
    }
}

// ---------------------------------------------------------------------------
// Readout: 32 rows staged; each weight load amortized over 2 rows (~160 us).
// ---------------------------------------------------------------------------
__global__ __launch_bounds__(512) void readout3(
    const float* __restrict__ rate_all,
    const float* __restrict__ Wt,   // [512][48] packed [Wo | Woc | pad]
    const float* __restrict__ bo, const float* __restrict__ boc,
    float* __restrict__ out, float* __restrict__ outc)
{
    __shared__ float rbuf[32][HH];  // 64 KB
    const int tid  = threadIdx.x;
    const size_t row0 = (size_t)blockIdx.x * 32;

    for (int i = tid; i < 32 * (HH / 4); i += 512) {
        int r = i >> 7, c = (i & 127) * 4;
        *(float4*)&rbuf[r][c] = *(const float4*)&rate_all[(row0 + r) * HH + c];
    }
    __syncthreads();

    {
        const int r = tid >> 5, o = tid & 31;
        const float* wt = Wt + o;
        float acc0 = 0.f, acc1 = 0.f;
        #pragma unroll 8
        for (int h = 0; h < HH; ++h) {
            float w = wt[(size_t)h * WT_LD];
            acc0 += rbuf[r][h] * w;
            acc1 += rbuf[r + 16][h] * w;
        }
        out[(row0 + r) * OO + o]      = acc0 + bo[o];
        out[(row0 + r + 16) * OO + o] = acc1 + bo[o];
    }
    if (tid < 128) {
        const int r = tid >> 3, c = tid & 7;
        const float* wt = Wt + OO + c;
        float acc0 = 0.f, acc1 = 0.f;
        #pragma unroll 8
        for (int h = 0; h < HH; ++h) {
            float w = wt[(size_t)h * WT_LD];
            acc0 += rbuf[r][h] * w;
            acc1 += rbuf[r + 16][h] * w;
        }
        outc[(row0 + r) * OCC + c]      = acc0 + boc[c];
        outc[(row0 + r + 16) * OCC + c] = acc1 + boc[c];
    }
}

// ---------------------------------------------------------------------------
extern "C" void kernel_launch(void* const* d_in, const int* in_sizes, int n_in,
                              void* d_out, int out_size, void* d_ws, size_t ws_size,
                              hipStream_t stream)
{
    const float* x     = (const float*)d_in[0];
    const float* rate0 = (const float*)d_in[1];
    const float* noise = (const float*)d_in[2];
    const float* Wi    = (const float*)d_in[3];
    const float* bi    = (const float*)d_in[4];
    const float* Wh    = (const float*)d_in[5];
    const float* bh    = (const float*)d_in[6];
    const float* Wo    = (const float*)d_in[7];
    const float* bo    = (const float*)d_in[8];
    const float* Woc   = (const float*)d_in[9];
    const float* boc   = (const float*)d_in[10];

    float* out   = (float*)d_out;
    float* rateb = out + RATE_OFF;
    float* P     = (float*)d_ws;
    int*   flags = (int*)((char*)d_ws + FLAG_BYTE_OFF);
    float* Wt    = (float*)((char*)d_ws + WT_BYTE_OFF);

    hipMemsetAsync(flags, 0, FLAG_BYTES, stream);   // ws is not re-poisoned
    pack_wt<<<(HH * WT_LD + 255) / 256, 256, 0, stream>>>(Wo, Woc, Wt);
    rnn_scan17<<<4 * BB, 1024, 0, stream>>>(x, rate0, noise, Wh, Wi, bi, bh,
                                            rateb, P, flags);
    readout3<<<TT * BB / 32, 512, 0, stream>>>(rateb, Wt, bo, boc,
                                               out, out + OUT1_OFF);
}